// Round 5
// baseline (44.862 us; speedup 1.0000x reference)
//
#include <hip/hip_runtime.h>

// GaussianAttention: y[b,s,i,j] = exp(-dist(b,i,j)^2 / (2*sigma_s^2))
// dist = L1 distance over D=3 dims; sigma_s = multiplier * base^s.
// Shape constants for this problem instance (fixed by the harness):
constexpr int B = 2;
constexpr int N = 2048;
constexpr int D = 3;
constexpr int H = 8;

// Each thread computes 4 consecutive j for one (b,i) row, all 8 heads.
// Block = 256 threads -> 1024 j's; grid.x = 2 covers N=2048; grid.y = B*N rows.
__global__ __launch_bounds__(256) void gauss_attn_kernel(
    const float* __restrict__ x,       // [B,N,D]
    const float* __restrict__ mult,    // [1]
    const float* __restrict__ base,    // [1]
    float* __restrict__ out)           // [B,H,N,N]
{
    const int row = blockIdx.y;          // b*N + i
    const int b   = row >> 11;           // row / N
    const int i   = row & (N - 1);
    const int j0  = (blockIdx.x * blockDim.x + threadIdx.x) * 4;

    // Per-head exponent scale: c2[s] = log2(e) / (2 * sigma_s^2),
    // built via recurrence (2 divides total instead of 8).
    const float m  = mult[0];
    const float bs = base[0];
    const float LOG2E = 1.4426950408889634f;
    const float c0     = LOG2E / (2.0f * m * m);
    const float inv_b2 = 1.0f / (bs * bs);
    float c2[H];
    c2[0] = c0;
    #pragma unroll
    for (int s = 1; s < H; ++s) c2[s] = c2[s - 1] * inv_b2;

    // Row-anchor point (uniform across block -> scalar loads).
    const float xi0 = x[row * 3 + 0];
    const float xi1 = x[row * 3 + 1];
    const float xi2 = x[row * 3 + 2];

    // 4 j-points = 12 consecutive floats = 3 aligned float4 loads.
    const float4* xj4 = reinterpret_cast<const float4*>(x + (size_t)(b * N + j0) * 3);
    const float4 a0 = xj4[0];
    const float4 a1 = xj4[1];
    const float4 a2 = xj4[2];

    const float jx[4] = {a0.x, a0.w, a1.z, a2.y};
    const float jy[4] = {a0.y, a1.x, a1.w, a2.z};
    const float jz[4] = {a0.z, a1.y, a2.x, a2.w};

    float t[4];
    #pragma unroll
    for (int q = 0; q < 4; ++q) {
        const float d = fabsf(xi0 - jx[q]) + fabsf(xi1 - jy[q]) + fabsf(xi2 - jz[q]);
        t[q] = -(d * d);
    }

    // 8 heads: one mul + one exp2 per element, float4 coalesced stores.
    #pragma unroll
    for (int s = 0; s < H; ++s) {
        float4 v;
        v.x = exp2f(t[0] * c2[s]);
        v.y = exp2f(t[1] * c2[s]);
        v.z = exp2f(t[2] * c2[s]);
        v.w = exp2f(t[3] * c2[s]);
        float* dst = out + ((size_t)(b * H + s) * N + i) * N + j0;
        *reinterpret_cast<float4*>(dst) = v;
    }
}

extern "C" void kernel_launch(void* const* d_in, const int* in_sizes, int n_in,
                              void* d_out, int out_size, void* d_ws, size_t ws_size,
                              hipStream_t stream) {
    const float* x    = (const float*)d_in[0];
    const float* mult = (const float*)d_in[1];
    const float* base = (const float*)d_in[2];
    float* out = (float*)d_out;

    const int threads = 256;
    dim3 grid(N / (threads * 4), B * N);   // (2, 4096)
    gauss_attn_kernel<<<grid, threads, 0, stream>>>(x, mult, base, out);
}